// Round 23
// baseline (206.460 us; speedup 1.0000x reference)
//
#include <hip/hip_runtime.h>
#include <math.h>

#define RR 1024
#define BB 16
#define DD 1024
#define K_ACTIVE 20

// clang native vector type for __builtin_nontemporal_store (rejects HIP float4).
typedef float f32x4 __attribute__((ext_vector_type(4)));

// ---------------------------------------------------------------------------
// Kernel 0: PURE WRITER, no dependencies. Zero-fill all of Hs with
// nontemporal stores. (Unchanged, verified.)
// ---------------------------------------------------------------------------
__global__ __launch_bounds__(256) void zero_fill_kernel(float* __restrict__ Hs)
{
    const f32x4 z = (f32x4){0.f, 0.f, 0.f, 0.f};
    f32x4* p = (f32x4*)Hs;
    const int n = RR * BB * DD / 4;                 // 4,194,304 f32x4
    for (int i = blockIdx.x * 256 + threadIdx.x; i < n; i += gridDim.x * 256)
        __builtin_nontemporal_store(z, &p[i]);
}

// ---------------------------------------------------------------------------
// Kernel 1: PURE READER via ASYNC global->LDS staging.
// Round-22 post-mortem: asm memory fence did NOT pin loads (VGPR stayed 36;
// invariant loads sink across clobbers). Register-file MLP is unreachable
// from source. This version sidesteps the register file: global_load_lds is
// vmcnt-tracked with ZERO dest VGPRs -> 8 loads in flight per wave by
// construction. Each wave owns one pair per round (private 8 KB LDS slice),
// so there is NO __syncthreads (no cross-wave sharing, no barrier drain):
//   issue 8x global_load_lds -> s_waitcnt vmcnt(0) -> ds_read + FMA + reduce.
// ---------------------------------------------------------------------------
__global__ __launch_bounds__(256) void score_kernel(
    const float* __restrict__ H, const float* __restrict__ msg,
    const float* __restrict__ w, const float* __restrict__ theta,
    const float* __restrict__ refr, const float* __restrict__ fb,
    float* __restrict__ adj_out)
{
    __shared__ float4 hbuf[4][256];   // one 4 KB slice per wave
    __shared__ float4 mbuf[4][256];   // one 4 KB slice per wave  (32 KB total)

    const int lane = threadIdx.x & 63;
    const int wv   = threadIdx.x >> 6;

    // w into registers once per wave (4 KB, L1/L2-hot broadcast).
    const float4* W4 = (const float4*)w;
    float4 ww[4];
#pragma unroll
    for (int k = 0; k < 4; ++k) ww[k] = W4[lane + 64 * k];

    for (int t = 0; t < 4; ++t) {
        const int pair = blockIdx.x * 16 + t * 4 + wv;   // 0..16383
        const int r = pair >> 4, b = pair & 15;

        const float4* Hp = (const float4*)(H   + (size_t)pair * DD);
        const float4* Mp = (const float4*)(msg + (size_t)pair * DD);

        // Issue 8 async 16B-wide loads (1 KB/inst/wave), zero VGPR cost.
        // LDS dest is wave-uniform base + lane*16 (linear), matching the
        // linear global layout chunk-for-chunk.
#pragma unroll
        for (int k = 0; k < 4; ++k) {
            __builtin_amdgcn_global_load_lds(
                (const __attribute__((address_space(1))) void*)(Hp + k * 64 + lane),
                (__attribute__((address_space(3))) void*)(&hbuf[wv][k * 64]),
                16, 0, 0);
            __builtin_amdgcn_global_load_lds(
                (const __attribute__((address_space(1))) void*)(Mp + k * 64 + lane),
                (__attribute__((address_space(3))) void*)(&mbuf[wv][k * 64]),
                16, 0, 0);
        }

        // Epilogue scalars issue here and complete under the vmcnt wait.
        const float th = theta[r];
        const float rf = refr[b * RR + r];
        const float f0 = fb[b * RR + r];

        asm volatile("s_waitcnt vmcnt(0)" ::: "memory");
        __builtin_amdgcn_sched_barrier(0);

        float dot = 0.f, ss = 0.f;
#pragma unroll
        for (int k = 0; k < 4; ++k) {
            const float4 hv = hbuf[wv][lane + 64 * k];
            const float4 mv = mbuf[wv][lane + 64 * k];
            dot += hv.x * ww[k].x + hv.y * ww[k].y + hv.z * ww[k].z + hv.w * ww[k].w;
            ss  += mv.x * mv.x + mv.y * mv.y + mv.z * mv.z + mv.w * mv.w;
        }
        // wave-64 reduction
#pragma unroll
        for (int off = 32; off > 0; off >>= 1) {
            dot += __shfl_down(dot, off);
            ss  += __shfl_down(ss, off);
        }
        if (lane == 0) {
            const float fbn = 0.9f * f0 + 0.1f * sqrtf(ss);
            adj_out[b * RR + r] = dot - th - rf - 0.5f * fbn;
        }
        // No barrier needed: this wave's next-round staging only issues after
        // the FMAs' lgkmcnt waits completed -> its own LDS slice is free.
    }
}

// ---------------------------------------------------------------------------
// Kernel 2 (fused NMS + selected-row gate): one block per batch, 256 threads.
// (Round-3 verified version, verbatim.)
// ---------------------------------------------------------------------------
__global__ __launch_bounds__(256) void nms_gate_kernel(
    const float* __restrict__ adj, const int* __restrict__ nbrs,
    const float* __restrict__ H,
    float* __restrict__ hard, float* __restrict__ Hs)
{
    __shared__ int nb_lds[RR * 6];            // 24 KiB
    __shared__ int sel_r[K_ACTIVE];
    __shared__ int nsel_lds;

    const int b = blockIdx.x;
    const int tid = threadIdx.x;
    const int lane = tid & 63;
    const int wave = tid >> 6;

    // Preload neighbor table: 6144 ints = 1536 int4, 6 int4 per thread.
    {
        const int4* nb4 = (const int4*)nbrs;
        int4* nl4 = (int4*)nb_lds;
#pragma unroll
        for (int j = 0; j < 6; ++j)
            nl4[tid + 256 * j] = nb4[tid + 256 * j];
    }
    __syncthreads();

    if (wave == 0) {
        float v[16];
#pragma unroll
        for (int j = 0; j < 16; ++j)
            v[j] = adj[b * RR + lane + 64 * j];

        unsigned int sel = 0u;    // bit j: region lane+64j selected
        unsigned int dead = 0u;   // bit j: region lane+64j suppressed/selected
        int nsel = 0;

        for (int it = 0; it < K_ACTIVE; ++it) {
            float tv[16]; int ti[16];
#pragma unroll
            for (int j = 0; j < 16; ++j) {
                tv[j] = ((dead >> j) & 1u) ? -INFINITY : v[j];
                ti[j] = lane + 64 * j;
            }
#pragma unroll
            for (int s = 8; s >= 1; s >>= 1) {
#pragma unroll
                for (int j = 0; j < 8; ++j) {
                    if (j < s) {
                        if (tv[j + s] > tv[j]) { tv[j] = tv[j + s]; ti[j] = ti[j + s]; }
                    }
                }
            }
            float m = tv[0];
            int mi = ti[0];

#pragma unroll
            for (int off = 32; off > 0; off >>= 1) {
                const float ov = __shfl_xor(m, off);
                const int   oi = __shfl_xor(mi, off);
                if (ov > m || (ov == m && oi < mi)) { m = ov; mi = oi; }
            }

            if (m == -INFINITY) break;   // parity with reference exhaustion

            if (lane == 0) sel_r[nsel] = mi;
            nsel++;

            int sup[7];
            sup[0] = mi;
            const int base = mi * 6;
#pragma unroll
            for (int k = 0; k < 6; ++k) sup[k + 1] = nb_lds[base + k];  // broadcast

            sel |= ((mi & 63) == lane) ? (1u << (mi >> 6)) : 0u;
#pragma unroll
            for (int k = 0; k < 7; ++k)
                dead |= ((sup[k] & 63) == lane) ? (1u << (sup[k] >> 6)) : 0u;
        }

        if (lane == 0) nsel_lds = nsel;

#pragma unroll
        for (int j = 0; j < 16; ++j)
            hard[b * RR + lane + 64 * j] = ((sel >> j) & 1u) ? 1.0f : 0.0f;
    }
    __syncthreads();

    // All 256 threads: copy selected rows H[r,b,:] -> Hs[r,b,:] (4 KB each).
    const int nsel = nsel_lds;
    for (int s = 0; s < nsel; ++s) {
        const int r = sel_r[s];
        const size_t off = ((size_t)r * BB + b) * DD;
        ((float4*)(Hs + off))[tid] = ((const float4*)(H + off))[tid];
    }
}

extern "C" void kernel_launch(void* const* d_in, const int* in_sizes, int n_in,
                              void* d_out, int out_size, void* d_ws, size_t ws_size,
                              hipStream_t stream) {
    const float* H     = (const float*)d_in[0];   // [R,B,D]
    const float* msg   = (const float*)d_in[1];   // [R,B,D]
    const float* w     = (const float*)d_in[2];   // [D]
    const float* theta = (const float*)d_in[3];   // [R]
    const float* refr  = (const float*)d_in[4];   // [B,R]
    const float* fb    = (const float*)d_in[5];   // [B,R]
    const int*   nbrs  = (const int*)d_in[6];     // [R,6]

    float* out  = (float*)d_out;
    float* Hs   = out;                                   // [R,B,D]
    float* hard = out + (size_t)RR * BB * DD;            // [B,R]
    float* adj  = hard + (size_t)BB * RR;                // [B,R]

    zero_fill_kernel<<<2048, 256, 0, stream>>>(Hs);
    score_kernel<<<1024, 256, 0, stream>>>(H, msg, w, theta, refr, fb, adj);
    nms_gate_kernel<<<BB, 256, 0, stream>>>(adj, nbrs, H, hard, Hs);
}